// Round 18
// baseline (248.585 us; speedup 1.0000x reference)
//
#include <hip/hip_runtime.h>

// Problem constants (fixed by the reference)
#define N2 2048
#define NNZ 32768
#define LK 22          // FROZEN: absmax 0.0234 of 0.037 threshold (3 of ~4.7 bf16 ulps)
#define NBL 128        // lanczos grid blocks: 128 x 512 thr; 147KB LDS -> 1 block/CU
#define BINCAP 64      // slots per bin (Poisson(16) tail ~1e-15)

typedef __attribute__((ext_vector_type(8))) _Float16 half8;
typedef __attribute__((ext_vector_type(4))) float f32x4;

#define AGENT __HIP_MEMORY_SCOPE_AGENT
#define AS1C(p) ((const __attribute__((address_space(1))) unsigned int*)(p))
#define AS3(p)  ((__attribute__((address_space(3))) unsigned int*)(p))

__device__ __forceinline__ unsigned short f2h(float f) {
  _Float16 h = (_Float16)f;                   // fp16 RNE
  return *(unsigned short*)&h;
}

// ==== R33 pipeline:  M = L A L^T,  L = I + S,  A = WW^T/N + I
//   = (L Wh)(L Wh)^T / N + I   [dense: gatherG + symmetric GEMM]
//   + S + S^T + S S^T          [sparse: traversed in-lanczos, chain-free]
// R17 ledger: gemmM ~48us = 1.5us/k-iter — the __syncthreads vmcnt(0) drain
// kills the double-buffer every iteration (documented m97-structure stall;
// Gh panels often L2-miss at ~900ns). R33: T4 counted-vmcnt minimum form —
// 3-buffer ring, depth-2 prefetch, raw s_barrier + s_waitcnt vmcnt(3)
// (never 0 in-loop). Math order unchanged => bitwise-identical results.

// ---- 1. W (fp32) -> fp16; zero row/col bin counters ----
__global__ __launch_bounds__(256) void convert_kernel(const float* __restrict__ W,
                                                      unsigned short* __restrict__ Hf,
                                                      unsigned* __restrict__ cntR,
                                                      unsigned* __restrict__ cntC) {
  if (blockIdx.x < 8)       cntR[blockIdx.x * 256 + threadIdx.x] = 0;
  else if (blockIdx.x < 16) cntC[(blockIdx.x - 8) * 256 + threadIdx.x] = 0;
  int i4 = blockIdx.x * 256 + threadIdx.x;          // grid 4096 -> 1048576 float4s
  float4 w = ((const float4*)W)[i4];
  ushort4 h;
  h.x = f2h(w.x); h.y = f2h(w.y); h.z = f2h(w.z); h.w = f2h(w.w);
  ((ushort4*)Hf)[i4] = h;
}

// ---- 2. fill row bins (G-gather, SS^T) and column bins (S^T, SS^T) ----
__global__ __launch_bounds__(256) void fill_kernel(const float* __restrict__ pred,
                                                   const float* __restrict__ scal,
                                                   const int* __restrict__ rows,
                                                   const int* __restrict__ cols,
                                                   unsigned* __restrict__ cntR,
                                                   int* __restrict__ binRc,
                                                   float* __restrict__ binRv,
                                                   unsigned* __restrict__ cntC,
                                                   int* __restrict__ binCr,
                                                   float* __restrict__ binCv) {
  int k = blockIdx.x * 256 + threadIdx.x;
  int r = rows[k], c = cols[k];
  float v = pred[k] * scal[k];
  unsigned pR = atomicAdd(&cntR[r], 1u);
  if (pR < BINCAP) { binRc[r * BINCAP + pR] = c; binRv[r * BINCAP + pR] = v; }
  unsigned pC = atomicAdd(&cntC[c], 1u);
  if (pC < BINCAP) { binCr[c * BINCAP + pC] = r; binCv[c * BINCAP + pC] = v; }
}

// ---- 3. G[r,:] = Hf[r,:] + sum_e v_e * Hf[c_e,:]  (fp16 out, fp32 acc, MLP-8) ----
__global__ __launch_bounds__(256) void gatherG_kernel(const unsigned* __restrict__ cntR,
                                                      const int* __restrict__ binRc,
                                                      const float* __restrict__ binRv,
                                                      const unsigned short* __restrict__ Hf,
                                                      unsigned short* __restrict__ Gh) {
  const int r = blockIdx.x, tid = threadIdx.x;
  __shared__ int scol_[BINCAP];
  __shared__ float sval_[BINCAP];
  const unsigned ne = min(cntR[r], (unsigned)BINCAP);
  if (tid < ne) {
    scol_[tid] = binRc[r * BINCAP + tid];
    sval_[tid] = binRv[r * BINCAP + tid];
  }
  __syncthreads();
  // init from own row (the I in L = I + S)
  uint4 own = *(const uint4*)(Hf + (size_t)r * 2048 + tid * 8);
  half8 ho = *(half8*)&own;
  float acc[8];
#pragma unroll
  for (int k = 0; k < 8; ++k) acc[k] = (float)ho[k];
  unsigned e = 0;
  for (; e + 8 <= ne; e += 8) {
    uint4 q[8];
#pragma unroll
    for (int u = 0; u < 8; ++u)
      q[u] = *(const uint4*)(Hf + (size_t)scol_[e + u] * 2048 + tid * 8);
#pragma unroll
    for (int u = 0; u < 8; ++u) {
      half8 hv = *(half8*)&q[u];
      const float v = sval_[e + u];
#pragma unroll
      for (int k = 0; k < 8; ++k) acc[k] += v * (float)hv[k];
    }
  }
  for (; e + 4 <= ne; e += 4) {
    uint4 q[4];
#pragma unroll
    for (int u = 0; u < 4; ++u)
      q[u] = *(const uint4*)(Hf + (size_t)scol_[e + u] * 2048 + tid * 8);
#pragma unroll
    for (int u = 0; u < 4; ++u) {
      half8 hv = *(half8*)&q[u];
      const float v = sval_[e + u];
#pragma unroll
      for (int k = 0; k < 8; ++k) acc[k] += v * (float)hv[k];
    }
  }
  for (; e < ne; ++e) {
    uint4 qq = *(const uint4*)(Hf + (size_t)scol_[e] * 2048 + tid * 8);
    half8 hv = *(half8*)&qq;
    const float v = sval_[e];
#pragma unroll
    for (int k = 0; k < 8; ++k) acc[k] += v * (float)hv[k];
  }
  unsigned short o[8];
#pragma unroll
  for (int k = 0; k < 8; ++k) o[k] = f2h(acc[k]);
  *(uint4*)(Gh + (size_t)r * 2048 + tid * 8) = *(uint4*)o;
}

// ---- 4. M = G*G^T/N + I — symmetric-half (R23), 3-ring counted-vmcnt (R33) ----
__device__ __forceinline__ void stage_tiles2(const unsigned short* __restrict__ X,
                                             unsigned short* Xb, unsigned short* Yb,
                                             int row0, int col0, int kk,
                                             int srowX, int srowY, int scol, int wq) {
  __builtin_amdgcn_global_load_lds(
      AS1C(X + (size_t)(row0 + srowX) * 2048 + kk + scol),
      AS3(Xb + (wq * 16) * 32), 16, 0, 0);
#pragma unroll
  for (int q = 0; q < 2; ++q) {
    __builtin_amdgcn_global_load_lds(
        AS1C(X + (size_t)(col0 + srowY + q * 16) * 2048 + kk + scol),
        AS3(Yb + (wq * 32 + q * 16) * 32), 16, 0, 0);
  }
}

__global__ __launch_bounds__(512) void gemmM_kernel(const unsigned short* __restrict__ Gh,
                                                    float* __restrict__ M) {
  const int tid = threadIdx.x;
  // tile mapping: 32 diag-band + 240 pure-lower (R23)
  int bi, bj;
  bool diag;
  if (blockIdx.x < 32) {
    bi = blockIdx.x; bj = bi >> 1; diag = true;
  } else {
    int idx = blockIdx.x - 32;                // 0..239
    int j = 0;                                 // off(j) = j*(31-j)
    while (j < 14 && idx >= (j + 1) * (30 - j)) ++j;
    bj = j;
    bi = 2 * j + 2 + (idx - j * (31 - j));
    diag = false;
  }

  // LDS: 3-ring staging 72KB (Xs 2half x 3buf x 64x32 = 24KB;
  // Ys 2half x 3buf x 128x32 = 48KB); Cred (33KB) aliases post-loop.
  // 72KB -> 2 blocks/CU; 272 blocks all resident.
  __shared__ __align__(16) char smem[73728];
  unsigned short* Xs = (unsigned short*)smem;
  unsigned short* Ys = (unsigned short*)(smem + 24576);
  float* Cred = (float*)smem;

  const int w = tid >> 6, lane = tid & 63;
  const int half = w >> 2, wq = w & 3;      // k-half, role within half
  const int row0 = bi * 64, col0 = bj * 128;
  const int m0 = (wq & 1) * 32, n0 = (wq >> 1) * 64;
  f32x4 acc[2][4];
#pragma unroll
  for (int a = 0; a < 2; ++a)
#pragma unroll
    for (int b = 0; b < 4; ++b) acc[a][b] = (f32x4){0.f, 0.f, 0.f, 0.f};
  const int mrow = lane & 15, kseg = (lane >> 4) * 8;
  const int srowX = wq * 16 + (lane >> 2);
  const int srowY = wq * 32 + (lane >> 2);
  const int scol = (lane & 3) * 8;
  const int kbase = half * 1024;

  // prologue: depth-2 prefetch (each stage = exactly 3 vmem ops per wave)
  stage_tiles2(Gh, Xs + (half * 3 + 0) * 2048, Ys + (half * 3 + 0) * 4096,
               row0, col0, kbase, srowX, srowY, scol, wq);
  stage_tiles2(Gh, Xs + (half * 3 + 1) * 2048, Ys + (half * 3 + 1) * 4096,
               row0, col0, kbase + 32, srowX, srowY, scol, wq);

  for (int t = 0; t < 32; ++t) {
    // wait tile t's 3 ops; keep tile t+1's 3 in flight (T4: never drain to 0)
    if (t < 31) asm volatile("s_waitcnt vmcnt(3)" ::: "memory");
    else        asm volatile("s_waitcnt vmcnt(0)" ::: "memory");
    __builtin_amdgcn_sched_barrier(0);
    __builtin_amdgcn_s_barrier();            // all waves: tile t resident,
    __builtin_amdgcn_sched_barrier(0);       // tile t-1 reads complete
    if (t + 2 < 32) {                        // stage t+2 into buf[(t+2)%3]
      const int nb = (t + 2) % 3;            // == (t-1)%3: safe post-barrier
      stage_tiles2(Gh, Xs + (half * 3 + nb) * 2048, Ys + (half * 3 + nb) * 4096,
                   row0, col0, kbase + (t + 2) * 32, srowX, srowY, scol, wq);
    }
    const int cb = t % 3;
    const unsigned short* Xb = Xs + (half * 3 + cb) * 2048;
    const unsigned short* Yb = Ys + (half * 3 + cb) * 4096;
    half8 af[2], bf[4];
#pragma unroll
    for (int q = 0; q < 2; ++q)
      af[q] = *(const half8*)(Xb + (m0 + q * 16 + mrow) * 32 + kseg);
#pragma unroll
    for (int q = 0; q < 4; ++q)
      bf[q] = *(const half8*)(Yb + (n0 + q * 16 + mrow) * 32 + kseg);
#pragma unroll
    for (int mt = 0; mt < 2; ++mt)
#pragma unroll
      for (int nt = 0; nt < 4; ++nt)
        acc[mt][nt] = __builtin_amdgcn_mfma_f32_16x16x32_f16(af[mt], bf[nt], acc[mt][nt], 0, 0, 0);
  }
  // combine halves; epilogue applies /N + I; fp32 direct + fp32 mirror.
  // C/D layout: col=lane&15, row=(lane>>4)*4+reg  [m89-verified]
  const int crow = (lane >> 4) * 4, ccol = lane & 15;
  __syncthreads();                           // full drain; Cred aliasing safe
  if (half == 1) {
#pragma unroll
    for (int mt = 0; mt < 2; ++mt)
#pragma unroll
      for (int nt = 0; nt < 4; ++nt)
#pragma unroll
        for (int r = 0; r < 4; ++r)
          Cred[(m0 + mt * 16 + crow + r) * 132 + n0 + nt * 16 + ccol] = acc[mt][nt][r];
  }
  __syncthreads();
  if (half == 0) {
    const float invn = 1.0f / 2048.0f;
#pragma unroll
    for (int mt = 0; mt < 2; ++mt)
#pragma unroll
      for (int nt = 0; nt < 4; ++nt) {
        const int gi0 = row0 + m0 + mt * 16 + crow;
        const int gj = col0 + n0 + nt * 16 + ccol;
        size_t base = (size_t)gi0 * 2048 + gj;
#pragma unroll
        for (int r = 0; r < 4; ++r) {
          const int li = (m0 + mt * 16 + crow + r) * 132 + n0 + nt * 16 + ccol;
          float val = (acc[mt][nt][r] + Cred[li]) * invn +
                      ((gi0 + r == gj) ? 1.0f : 0.0f);
          M[base + (size_t)r * 2048] = val;
          if (!diag) Cred[li] = val;        // park final value for mirror pass
        }
      }
  }
  if (!diag) {
    __syncthreads();                         // Cred holds the final fp32 tile
    const int orow = tid >> 2;               // 0..127 (original tile col)
    const int cseg = (tid & 3) * 16;         // 0..48  (original tile row base)
    float mv[16];
#pragma unroll
    for (int k = 0; k < 16; ++k)
      mv[k] = Cred[(cseg + k) * 132 + orow];
    float4* dst = (float4*)(M + (size_t)(col0 + orow) * 2048 + row0 + cseg);
    dst[0] = (float4){mv[0], mv[1], mv[2], mv[3]};
    dst[1] = (float4){mv[4], mv[5], mv[6], mv[7]};
    dst[2] = (float4){mv[8], mv[9], mv[10], mv[11]};
    dst[3] = (float4){mv[12], mv[13], mv[14], mv[15]};
  }
}

// ---- deterministic block-wide sum over 8 waves: bitwise-identical per block ----
__device__ __forceinline__ float block_sum8(float v, float* red) {
#pragma unroll
  for (int off = 32; off; off >>= 1) v += __shfl_down(v, off);
  if ((threadIdx.x & 63) == 0) red[threadIdx.x >> 6] = v;
  __syncthreads();
  float r = ((red[0] + red[1]) + (red[2] + red[3])) +
            ((red[4] + red[5]) + (red[6] + red[7]));
  __syncthreads();
  return r;
}

// ---- 5. Lanczos: single-phase epoch protocol, 128 x 512 — FROZEN core (R20) ----
// R20: ~4.2 us/iter exchange is the store->remote-observability floor.
// RULE 1 (R1/R6): cross-block data via agent-scope atomics only.
// RULE 2 (R1/R6/R8): beta^2 = ||z - alpha v||^2 DIRECT form only.
// RULE 3 (R16): no fixed-address staging reuse with plain cached loads.
// RULE 4 (R17): exactly ONE publish->consume phase per iteration.
// RULE 5 (R19/R20): exchange cost is per-phase visibility latency.
// RULE 6 (R14/R15): no serial dependent-load chains anywhere.
// R32: sparse term S + S^T + SS^T traversed in-kernel (chain-free).
__global__ __launch_bounds__(512) void lanczos_kernel(const float* __restrict__ M,
                                                      const unsigned* __restrict__ cntR,
                                                      const int* __restrict__ binRc,
                                                      const float* __restrict__ binRv,
                                                      const unsigned* __restrict__ cntC,
                                                      const int* __restrict__ binCr,
                                                      const float* __restrict__ binCv,
                                                      unsigned long long* __restrict__ Z0,
                                                      unsigned long long* __restrict__ Z1,
                                                      float* __restrict__ out) {
  const int tid = threadIdx.x, b = blockIdx.x;
  const int wave = tid >> 6, lane = tid & 63;
  __shared__ __align__(16) float Mlds[16 * 2048];  // 128 KB: this block's 16 rows
  __shared__ __align__(16) float VA[2048];
  __shared__ __align__(16) float VB[2048];
  __shared__ float red[8];
  __shared__ float al[LK + 2], b2[LK + 2];
  __shared__ float bnds[2], res[2];

  const float* Mblk = M + (size_t)b * 16 * 2048;
#pragma unroll
  for (int q = 0; q < 16; ++q)
    __builtin_amdgcn_global_load_lds(AS1C(Mblk + wave * 4096 + q * 256 + lane * 4),
                                     AS3(Mlds + wave * 4096 + q * 256), 16, 0, 0);

  // block-redundant init: v1 = hash / ||hash||  (identical in every block), v0 = 0
  float pv[4];
  float part = 0.f;
#pragma unroll
  for (int t = 0; t < 4; ++t) {
    int i = t * 512 + tid;
    unsigned u = (unsigned)i * 2654435761u;
    u ^= u >> 16; u *= 2246822519u; u ^= u >> 13;
    float rv = (float)(u >> 8) * (2.f / 16777216.f) - 1.f;
    pv[t] = rv;
    part += rv * rv;
  }
  float nrm = block_sum8(part, red);       // barriers inside drain Mlds staging
  float innm = rsqrtf(nrm);
#pragma unroll
  for (int t = 0; t < 4; ++t) {
    int i = t * 512 + tid;
    VA[i] = pv[t] * innm;
    VB[i] = 0.f;
  }
  __syncthreads();                         // Mlds fully staged; VA/VB ready

  // ---- R32: in-kernel sparse traversal for this block's rows ----
  for (int rr = 0; rr < 2; ++rr) {
    const int r = b * 16 + wave * 2 + rr;
    float* Mrow = Mlds + (wave * 2 + rr) * 2048;
    const unsigned nR = min(cntR[r], (unsigned)BINCAP);
    const unsigned nC = min(cntC[r], (unsigned)BINCAP);
    // lane e holds row-bin entry e (parallel loads; one dependent hop to cntC)
    int c_ = 0; float v_ = 0.f; unsigned n_ = 0;
    if (lane < nR) {
      c_ = binRc[r * BINCAP + lane];
      v_ = binRv[r * BINCAP + lane];
      n_ = min(cntC[c_], (unsigned)BINCAP);
    }
    // S: M[r, c_e] += v_e
    if (lane < nR) atomicAdd(&Mrow[c_], v_);
    // S^T: column bin r -> M[r, j_e] += v_e
    if (lane < nC)
      atomicAdd(&Mrow[binCr[r * BINCAP + lane]], binCv[r * BINCAP + lane]);
    // SS^T: group g (16 lanes) expands entry e = g, g+4, ... via shfl-broadcast
    const unsigned g = lane >> 4, p0 = lane & 15;
    for (unsigned e = g; e < nR; e += 4) {
      const int c = __shfl(c_, (int)e);
      const float v = __shfl(v_, (int)e);
      const unsigned n2 = __shfl(n_, (int)e);
      for (unsigned p = p0; p < n2; p += 16)
        atomicAdd(&Mrow[binCr[c * BINCAP + p]], v * binCv[c * BINCAP + p]);
    }
  }
  __syncthreads();                         // sparse apply complete

  float* Vcur = VA;
  float* Vprev = VB;
  float beta_prev = 0.f;

  for (int j = 1; j <= LK; ++j) {
    unsigned long long* Z = (j & 1) ? Z0 : Z1;
#pragma unroll
    for (int rr = 0; rr < 2; ++rr) {
      const int r = b * 16 + wave * 2 + rr;
      const float4* Mr = (const float4*)(Mlds + (wave * 2 + rr) * 2048);
      float s = 0.f;
#pragma unroll
      for (int t = 0; t < 8; ++t) {
        int idx = t * 64 + lane;
        float4 m4 = Mr[idx];
        float4 v4 = ((const float4*)Vcur)[idx];
        s += m4.x * v4.x + m4.y * v4.y + m4.z * v4.z + m4.w * v4.w;
      }
#pragma unroll
      for (int off = 32; off; off >>= 1) s += __shfl_down(s, off);
      if (lane == 0) {
        float zv = s - beta_prev * Vprev[r];
        unsigned long long pk = ((unsigned long long)(unsigned)j << 32) |
                                (unsigned long long)(unsigned)__float_as_uint(zv);
        __hip_atomic_store(&Z[r], pk, __ATOMIC_RELAXED, AGENT);
      }
    }

    // hoist own v-slice reads (LDS) ahead of the poll — free overlap
    float va[4];
#pragma unroll
    for (int t = 0; t < 4; ++t) va[t] = Vcur[t * 512 + tid];

    unsigned long long w4[4];
    int rounds = 0;
    for (;;) {
      bool ok = true;
#pragma unroll
      for (int t = 0; t < 4; ++t) {
        w4[t] = __hip_atomic_load(&Z[t * 512 + tid], __ATOMIC_RELAXED, AGENT);
        ok &= ((unsigned)(w4[t] >> 32) == (unsigned)j);
      }
      if (ok) break;
      if (rounds == 1)      __builtin_amdgcn_s_sleep(1);   //  64 clk
      else if (rounds == 2) __builtin_amdgcn_s_sleep(2);   // 128 clk
      else if (rounds >= 3) __builtin_amdgcn_s_sleep(8);   // 512 clk
      ++rounds;
    }
    float za[4];
    float pa = 0.f;
#pragma unroll
    for (int t = 0; t < 4; ++t) {
      za[t] = __uint_as_float((unsigned)w4[t]);
      pa += za[t] * va[t];
    }
    float alpha = block_sum8(pa, red);
    float pb = 0.f;
#pragma unroll
    for (int t = 0; t < 4; ++t) {
      float rsd = za[t] - alpha * va[t];
      pb += rsd * rsd;
    }
    float beta2 = block_sum8(pb, red);
    float beta = sqrtf(fmaxf(beta2, 1e-30f));
    float invb = 1.f / beta;
    if (tid == 0) { al[j] = alpha; b2[j] = beta2; }
#pragma unroll
    for (int t = 0; t < 4; ++t) {
      int i = t * 512 + tid;
      Vprev[i] = (za[t] - alpha * va[t]) * invb;
    }
    float* tmp = Vprev; Vprev = Vcur; Vcur = tmp;
    beta_prev = beta;
    __syncthreads();
  }

  // ---- extreme eigenvalues of T via Sturm bisection (block 0) ----
  if (b == 0) {
    if (tid == 0) {                                  // Gershgorin bounds on T
      float lo = 1e30f, hi = -1e30f;
      for (int i = 1; i <= LK; ++i) {
        float bl = (i > 1) ? sqrtf(b2[i - 1]) : 0.f;
        float br = (i < LK) ? sqrtf(b2[i]) : 0.f;
        lo = fminf(lo, al[i] - bl - br);
        hi = fmaxf(hi, al[i] + bl + br);
      }
      bnds[0] = lo; bnds[1] = hi;
    }
    __syncthreads();
    if (wave < 2) {                 // wave 0 -> lambda_min, wave 1 -> lambda_max
      const int tcount = (wave == 0) ? 1 : LK;
      float lo = bnds[0], hi = bnds[1];
      for (int round = 0; round < 4; ++round) {
        float x = lo + (hi - lo) * (float)(lane + 1) * (1.f / 65.f);
        int cnt = 0;                                 // #eigs of T below x
        float d = al[1] - x;
        if (fabsf(d) < 1e-25f) d = -1e-25f;
        if (d < 0.f) cnt++;
        for (int i = 2; i <= LK; ++i) {
          d = (al[i] - x) - b2[i - 1] / d;
          if (fabsf(d) < 1e-25f) d = -1e-25f;
          if (d < 0.f) cnt++;
        }
        bool ab = (cnt >= tcount);                   // x is above the target eig
        float cand_hi = ab ? x : hi;
        float cand_lo = ab ? lo : x;
#pragma unroll
        for (int off = 32; off; off >>= 1) {
          cand_hi = fminf(cand_hi, __shfl_down(cand_hi, off));
          cand_lo = fmaxf(cand_lo, __shfl_down(cand_lo, off));
        }
        cand_hi = __shfl(cand_hi, 0);
        cand_lo = __shfl(cand_lo, 0);
        hi = cand_hi;
        lo = fminf(cand_lo, hi);
      }
      if (lane == 0) res[wave] = 0.5f * (lo + hi);
    }
    __syncthreads();
    if (tid == 0) {
      float lmin = fmaxf(res[0], 1e-12f);
      float lmax = fmaxf(res[1], 1e-12f);
      out[0] = logf(lmax) - logf(lmin);
    }
  }
}

extern "C" void kernel_launch(void* const* d_in, const int* in_sizes, int n_in,
                              void* d_out, int out_size, void* d_ws, size_t ws_size,
                              hipStream_t stream) {
  const float* pred = (const float*)d_in[0];
  const float* scal = (const float*)d_in[1];
  const float* W    = (const float*)d_in[2];
  const int*   rows = (const int*)d_in[3];
  const int*   cols = (const int*)d_in[4];
  float* out = (float*)d_out;

  // workspace layout (peak ~34.2 MB):
  //  [0,8MB)   : Hf fp16
  //  [8,16MB)  : Gh fp16 (G = L*Wh)
  //  [16,32MB) : M fp32
  //  [32MB,..) : cntR 8KB | cntC 8KB | binRc 512KB | binRv 512KB |
  //              binCr 512KB | binCv 512KB | Z0 16KB | Z1 16KB
  char* ws = (char*)d_ws;
  const size_t MB = 1024 * 1024;
  unsigned short* Hf = (unsigned short*)(ws);
  unsigned short* Gh = (unsigned short*)(ws + 8 * MB);
  float* M = (float*)(ws + 16 * MB);
  char* ctrl = ws + 32 * MB;
  unsigned* cntR = (unsigned*)(ctrl);
  unsigned* cntC = (unsigned*)(ctrl + 8192);
  int*      binRc = (int*)(ctrl + 16384);
  float*    binRv = (float*)(ctrl + 16384 + 524288);
  int*      binCr = (int*)(ctrl + 16384 + 2 * 524288);
  float*    binCv = (float*)(ctrl + 16384 + 3 * 524288);
  unsigned long long* Z0 = (unsigned long long*)(ctrl + 16384 + 4 * 524288);
  unsigned long long* Z1 = (unsigned long long*)(ctrl + 16384 + 4 * 524288 + 16384);

  convert_kernel<<<4096, 256, 0, stream>>>(W, Hf, cntR, cntC);
  fill_kernel<<<NNZ / 256, 256, 0, stream>>>(pred, scal, rows, cols,
                                             cntR, binRc, binRv, cntC, binCr, binCv);
  gatherG_kernel<<<2048, 256, 0, stream>>>(cntR, binRc, binRv, Hf, Gh);  // G = L*Wh
  gemmM_kernel<<<272, 512, 0, stream>>>(Gh, M);                          // M = GG^T/N + I
  lanczos_kernel<<<NBL, 512, 0, stream>>>(M, cntR, binRc, binRv,
                                          cntC, binCr, binCv, Z0, Z1, out);
}

// Round 19
// 245.391 us; speedup vs baseline: 1.0130x; 1.0130x over previous
//
#include <hip/hip_runtime.h>

// Problem constants (fixed by the reference)
#define N2 2048
#define NNZ 32768
#define LK 22          // FROZEN: absmax 0.0234 of 0.037 threshold (3 of ~4.7 bf16 ulps)
#define NBL 128        // lanczos grid blocks: 128 x 512 thr; 147KB LDS -> 1 block/CU
#define BINCAP 64      // slots per bin (Poisson(16) tail ~1e-15)

typedef __attribute__((ext_vector_type(8))) _Float16 half8;
typedef __attribute__((ext_vector_type(4))) float f32x4;

#define AGENT __HIP_MEMORY_SCOPE_AGENT
#define AS1C(p) ((const __attribute__((address_space(1))) unsigned int*)(p))
#define AS3(p)  ((__attribute__((address_space(3))) unsigned int*)(p))

__device__ __forceinline__ unsigned short f2h(float f) {
  _Float16 h = (_Float16)f;                   // fp16 RNE
  return *(unsigned short*)&h;
}

// ==== R34 pipeline:  M = L A L^T,  L = I + S,  A = WW^T/N + I
//   = (L Wh)(L Wh)^T / N + I   [dense: gatherG + symmetric GEMM]
//   + S + S^T + S S^T          [sparse: traversed in-lanczos, chain-free]
// R18 ledger: 4 schedule levers on gemmM all null -> gemmM is BYTE/BANK-bound:
// 209MB of L3 panel re-reads (96 B/output elem at 64x128 tiles) + an 8-way
// LDS bank conflict in the frag reads (64B rows: 16 mrow lanes stride 16
// dwords -> 2 banks). R34: 128x128 tiles BK=64 (64 B/elem -> 139MB), XOR
// swizzle byte^=(row&7)<<4 (2-way, free) with pre-swizzled global source
// (rule 21: linear dest + inverse-swz source + swz read), no split-K.

// ---- 1. W (fp32) -> fp16; zero row/col bin counters ----
__global__ __launch_bounds__(256) void convert_kernel(const float* __restrict__ W,
                                                      unsigned short* __restrict__ Hf,
                                                      unsigned* __restrict__ cntR,
                                                      unsigned* __restrict__ cntC) {
  if (blockIdx.x < 8)       cntR[blockIdx.x * 256 + threadIdx.x] = 0;
  else if (blockIdx.x < 16) cntC[(blockIdx.x - 8) * 256 + threadIdx.x] = 0;
  int i4 = blockIdx.x * 256 + threadIdx.x;          // grid 4096 -> 1048576 float4s
  float4 w = ((const float4*)W)[i4];
  ushort4 h;
  h.x = f2h(w.x); h.y = f2h(w.y); h.z = f2h(w.z); h.w = f2h(w.w);
  ((ushort4*)Hf)[i4] = h;
}

// ---- 2. fill row bins (G-gather, SS^T) and column bins (S^T, SS^T) ----
__global__ __launch_bounds__(256) void fill_kernel(const float* __restrict__ pred,
                                                   const float* __restrict__ scal,
                                                   const int* __restrict__ rows,
                                                   const int* __restrict__ cols,
                                                   unsigned* __restrict__ cntR,
                                                   int* __restrict__ binRc,
                                                   float* __restrict__ binRv,
                                                   unsigned* __restrict__ cntC,
                                                   int* __restrict__ binCr,
                                                   float* __restrict__ binCv) {
  int k = blockIdx.x * 256 + threadIdx.x;
  int r = rows[k], c = cols[k];
  float v = pred[k] * scal[k];
  unsigned pR = atomicAdd(&cntR[r], 1u);
  if (pR < BINCAP) { binRc[r * BINCAP + pR] = c; binRv[r * BINCAP + pR] = v; }
  unsigned pC = atomicAdd(&cntC[c], 1u);
  if (pC < BINCAP) { binCr[c * BINCAP + pC] = r; binCv[c * BINCAP + pC] = v; }
}

// ---- 3. G[r,:] = Hf[r,:] + sum_e v_e * Hf[c_e,:]  (fp16 out, fp32 acc, MLP-8) ----
__global__ __launch_bounds__(256) void gatherG_kernel(const unsigned* __restrict__ cntR,
                                                      const int* __restrict__ binRc,
                                                      const float* __restrict__ binRv,
                                                      const unsigned short* __restrict__ Hf,
                                                      unsigned short* __restrict__ Gh) {
  const int r = blockIdx.x, tid = threadIdx.x;
  __shared__ int scol_[BINCAP];
  __shared__ float sval_[BINCAP];
  const unsigned ne = min(cntR[r], (unsigned)BINCAP);
  if (tid < ne) {
    scol_[tid] = binRc[r * BINCAP + tid];
    sval_[tid] = binRv[r * BINCAP + tid];
  }
  __syncthreads();
  // init from own row (the I in L = I + S)
  uint4 own = *(const uint4*)(Hf + (size_t)r * 2048 + tid * 8);
  half8 ho = *(half8*)&own;
  float acc[8];
#pragma unroll
  for (int k = 0; k < 8; ++k) acc[k] = (float)ho[k];
  unsigned e = 0;
  for (; e + 8 <= ne; e += 8) {
    uint4 q[8];
#pragma unroll
    for (int u = 0; u < 8; ++u)
      q[u] = *(const uint4*)(Hf + (size_t)scol_[e + u] * 2048 + tid * 8);
#pragma unroll
    for (int u = 0; u < 8; ++u) {
      half8 hv = *(half8*)&q[u];
      const float v = sval_[e + u];
#pragma unroll
      for (int k = 0; k < 8; ++k) acc[k] += v * (float)hv[k];
    }
  }
  for (; e + 4 <= ne; e += 4) {
    uint4 q[4];
#pragma unroll
    for (int u = 0; u < 4; ++u)
      q[u] = *(const uint4*)(Hf + (size_t)scol_[e + u] * 2048 + tid * 8);
#pragma unroll
    for (int u = 0; u < 4; ++u) {
      half8 hv = *(half8*)&q[u];
      const float v = sval_[e + u];
#pragma unroll
      for (int k = 0; k < 8; ++k) acc[k] += v * (float)hv[k];
    }
  }
  for (; e < ne; ++e) {
    uint4 qq = *(const uint4*)(Hf + (size_t)scol_[e] * 2048 + tid * 8);
    half8 hv = *(half8*)&qq;
    const float v = sval_[e];
#pragma unroll
    for (int k = 0; k < 8; ++k) acc[k] += v * (float)hv[k];
  }
  unsigned short o[8];
#pragma unroll
  for (int k = 0; k < 8; ++k) o[k] = f2h(acc[k]);
  *(uint4*)(Gh + (size_t)r * 2048 + tid * 8) = *(uint4*)o;
}

// ---- 4. M = G*G^T/N + I — 128x128 tiles, BK=64, XOR-swizzled LDS (R34) ----
// Staging: wave w stages rows [w*16, w*16+16) of X and Y panels; 2 issues
// each (8 rows x 128B per issue). LDS dest linear (wave-uniform base +
// lane*16); global SOURCE col pre-swizzled: srcc = (lane&7)*16 ^ ((lane>>3)<<4)
// so that LDS slot (row, slotbyte) holds global col slotbyte^((row&7)<<4).
__device__ __forceinline__ void stageXY(const unsigned short* __restrict__ Gh,
                                        char* Xb, char* Yb,
                                        int row0, int col0, int k0,
                                        int w, int lane) {
  const int srcc = ((lane & 7) * 16) ^ ((lane >> 3) << 4);
#pragma unroll
  for (int q = 0; q < 2; ++q) {
    const int rl = w * 16 + q * 8 + (lane >> 3);          // local row
    __builtin_amdgcn_global_load_lds(
        AS1C((const char*)(Gh + (size_t)(row0 + rl) * 2048 + k0) + srcc),
        AS3(Xb + (w * 16 + q * 8) * 128), 16, 0, 0);
    __builtin_amdgcn_global_load_lds(
        AS1C((const char*)(Gh + (size_t)(col0 + rl) * 2048 + k0) + srcc),
        AS3(Yb + (w * 16 + q * 8) * 128), 16, 0, 0);
  }
}

__global__ __launch_bounds__(512) void gemmM_kernel(const unsigned short* __restrict__ Gh,
                                                    float* __restrict__ M) {
  const int tid = threadIdx.x;
  // tile mapping: 16 diag (bi==bj, symmetric tile, full write) +
  //               120 strict-lower (bi>bj, direct + mirrored write)
  int bi, bj;
  bool diag;
  if (blockIdx.x < 16) {
    bi = bj = blockIdx.x; diag = true;
  } else {
    int idx = blockIdx.x - 16;               // 0..119
    int j = 0;                                // off(j) = 15j - j(j-1)/2
    while (j < 15) {
      int offn = 15 * (j + 1) - (j + 1) * j / 2;
      if (idx < offn) break;
      ++j;
    }
    bj = j;
    int off = 15 * j - j * (j - 1) / 2;
    bi = j + 1 + (idx - off);
    diag = false;
  }

  // LDS 64KB: Xs[2][128][64]fp16 @0,16K; Ys[2][128][64] @32K,48K.
  // Mirror chunks (4 x 16x132 f32 = 33.8KB) alias post-loop.
  __shared__ __align__(16) char smem[65536];
  float* LDSf = (float*)smem;

  const int w = tid >> 6, lane = tid & 63;
  const int row0 = bi * 128, col0 = bj * 128;
  const int mrow = lane & 15;
  const int crow = (lane >> 4) * 4, ccol = lane & 15;
  f32x4 acc[8];
#pragma unroll
  for (int n = 0; n < 8; ++n) acc[n] = (f32x4){0.f, 0.f, 0.f, 0.f};

  // prologue: stage k-tile 0 into buffer 0
  stageXY(Gh, smem, smem + 32768, row0, col0, 0, w, lane);

  const int arow = w * 16 + mrow;            // A-frag local row
  const int xswA = (mrow & 7) << 4;          // read-side XOR (row&7)<<4
  for (int t = 0; t < 32; ++t) {
    __syncthreads();                         // buf[t&1] resident; prev reads done
    if (t < 31)
      stageXY(Gh, smem + ((t + 1) & 1) * 16384, smem + 32768 + ((t + 1) & 1) * 16384,
              row0, col0, (t + 1) * 64, w, lane);
    const char* Xb = smem + (t & 1) * 16384;
    const char* Yb = smem + 32768 + (t & 1) * 16384;
#pragma unroll
    for (int kk = 0; kk < 2; ++kk) {
      const int cb = kk * 64 + (lane >> 4) * 16;   // byte col of 16B frag
      half8 af = *(const half8*)(Xb + arow * 128 + (cb ^ xswA));
#pragma unroll
      for (int nt = 0; nt < 8; ++nt) {
        const int nrow = nt * 16 + mrow;
        half8 bf = *(const half8*)(Yb + nrow * 128 + (cb ^ ((nrow & 7) << 4)));
        acc[nt] = __builtin_amdgcn_mfma_f32_16x16x32_f16(af, bf, acc[nt], 0, 0, 0);
      }
    }
  }
  // ---- epilogue: direct write (always); mirror via LDS chunk (lower tiles) ----
  // C/D layout: col=lane&15, row=(lane>>4)*4+reg  [m89-verified]
  const float invn = 1.0f / 2048.0f;
  float vals[8][4];
#pragma unroll
  for (int nt = 0; nt < 8; ++nt) {
    const int gj = col0 + nt * 16 + ccol;
#pragma unroll
    for (int r = 0; r < 4; ++r) {
      const int gi = row0 + w * 16 + crow + r;
      float v = acc[nt][r] * invn + ((gi == gj) ? 1.0f : 0.0f);
      vals[nt][r] = v;
      M[(size_t)gi * 2048 + gj] = v;
    }
  }
  if (!diag) {
    __syncthreads();                         // staging reads done; LDSf safe
    for (int round = 0; round < 2; ++round) {
      if ((w >> 2) == round) {
        float* myc = LDSf + (w & 3) * (16 * 132);   // [16][132]
#pragma unroll
        for (int nt = 0; nt < 8; ++nt)
#pragma unroll
          for (int r = 0; r < 4; ++r)
            myc[(crow + r) * 132 + nt * 16 + ccol] = vals[nt][r];
        // same-wave LDS write->read (compiler inserts lgkmcnt waits)
        for (int u = 0; u < 32; ++u) {
          const int jj = u * 4 + (lane >> 4);       // tile col 0..127
          const int ii = lane & 15;                 // tile row-in-strip 0..15
          M[(size_t)(col0 + jj) * 2048 + row0 + w * 16 + ii] = myc[ii * 132 + jj];
        }
      }
      __syncthreads();
    }
  }
}

// ---- deterministic block-wide sum over 8 waves: bitwise-identical per block ----
__device__ __forceinline__ float block_sum8(float v, float* red) {
#pragma unroll
  for (int off = 32; off; off >>= 1) v += __shfl_down(v, off);
  if ((threadIdx.x & 63) == 0) red[threadIdx.x >> 6] = v;
  __syncthreads();
  float r = ((red[0] + red[1]) + (red[2] + red[3])) +
            ((red[4] + red[5]) + (red[6] + red[7]));
  __syncthreads();
  return r;
}

// ---- 5. Lanczos: single-phase epoch protocol, 128 x 512 — FROZEN core (R20) ----
// R20: ~4.2 us/iter exchange is the store->remote-observability floor.
// RULE 1 (R1/R6): cross-block data via agent-scope atomics only.
// RULE 2 (R1/R6/R8): beta^2 = ||z - alpha v||^2 DIRECT form only.
// RULE 3 (R16): no fixed-address staging reuse with plain cached loads.
// RULE 4 (R17): exactly ONE publish->consume phase per iteration.
// RULE 5 (R19/R20): exchange cost is per-phase visibility latency.
// RULE 6 (R14/R15): no serial dependent-load chains anywhere.
// R32: sparse term S + S^T + SS^T traversed in-kernel (chain-free).
__global__ __launch_bounds__(512) void lanczos_kernel(const float* __restrict__ M,
                                                      const unsigned* __restrict__ cntR,
                                                      const int* __restrict__ binRc,
                                                      const float* __restrict__ binRv,
                                                      const unsigned* __restrict__ cntC,
                                                      const int* __restrict__ binCr,
                                                      const float* __restrict__ binCv,
                                                      unsigned long long* __restrict__ Z0,
                                                      unsigned long long* __restrict__ Z1,
                                                      float* __restrict__ out) {
  const int tid = threadIdx.x, b = blockIdx.x;
  const int wave = tid >> 6, lane = tid & 63;
  __shared__ __align__(16) float Mlds[16 * 2048];  // 128 KB: this block's 16 rows
  __shared__ __align__(16) float VA[2048];
  __shared__ __align__(16) float VB[2048];
  __shared__ float red[8];
  __shared__ float al[LK + 2], b2[LK + 2];
  __shared__ float bnds[2], res[2];

  const float* Mblk = M + (size_t)b * 16 * 2048;
#pragma unroll
  for (int q = 0; q < 16; ++q)
    __builtin_amdgcn_global_load_lds(AS1C(Mblk + wave * 4096 + q * 256 + lane * 4),
                                     AS3(Mlds + wave * 4096 + q * 256), 16, 0, 0);

  // block-redundant init: v1 = hash / ||hash||  (identical in every block), v0 = 0
  float pv[4];
  float part = 0.f;
#pragma unroll
  for (int t = 0; t < 4; ++t) {
    int i = t * 512 + tid;
    unsigned u = (unsigned)i * 2654435761u;
    u ^= u >> 16; u *= 2246822519u; u ^= u >> 13;
    float rv = (float)(u >> 8) * (2.f / 16777216.f) - 1.f;
    pv[t] = rv;
    part += rv * rv;
  }
  float nrm = block_sum8(part, red);       // barriers inside drain Mlds staging
  float innm = rsqrtf(nrm);
#pragma unroll
  for (int t = 0; t < 4; ++t) {
    int i = t * 512 + tid;
    VA[i] = pv[t] * innm;
    VB[i] = 0.f;
  }
  __syncthreads();                         // Mlds fully staged; VA/VB ready

  // ---- R32: in-kernel sparse traversal for this block's rows ----
  for (int rr = 0; rr < 2; ++rr) {
    const int r = b * 16 + wave * 2 + rr;
    float* Mrow = Mlds + (wave * 2 + rr) * 2048;
    const unsigned nR = min(cntR[r], (unsigned)BINCAP);
    const unsigned nC = min(cntC[r], (unsigned)BINCAP);
    // lane e holds row-bin entry e (parallel loads; one dependent hop to cntC)
    int c_ = 0; float v_ = 0.f; unsigned n_ = 0;
    if (lane < nR) {
      c_ = binRc[r * BINCAP + lane];
      v_ = binRv[r * BINCAP + lane];
      n_ = min(cntC[c_], (unsigned)BINCAP);
    }
    // S: M[r, c_e] += v_e
    if (lane < nR) atomicAdd(&Mrow[c_], v_);
    // S^T: column bin r -> M[r, j_e] += v_e
    if (lane < nC)
      atomicAdd(&Mrow[binCr[r * BINCAP + lane]], binCv[r * BINCAP + lane]);
    // SS^T: group g (16 lanes) expands entry e = g, g+4, ... via shfl-broadcast
    const unsigned g = lane >> 4, p0 = lane & 15;
    for (unsigned e = g; e < nR; e += 4) {
      const int c = __shfl(c_, (int)e);
      const float v = __shfl(v_, (int)e);
      const unsigned n2 = __shfl(n_, (int)e);
      for (unsigned p = p0; p < n2; p += 16)
        atomicAdd(&Mrow[binCr[c * BINCAP + p]], v * binCv[c * BINCAP + p]);
    }
  }
  __syncthreads();                         // sparse apply complete

  float* Vcur = VA;
  float* Vprev = VB;
  float beta_prev = 0.f;

  for (int j = 1; j <= LK; ++j) {
    unsigned long long* Z = (j & 1) ? Z0 : Z1;
#pragma unroll
    for (int rr = 0; rr < 2; ++rr) {
      const int r = b * 16 + wave * 2 + rr;
      const float4* Mr = (const float4*)(Mlds + (wave * 2 + rr) * 2048);
      float s = 0.f;
#pragma unroll
      for (int t = 0; t < 8; ++t) {
        int idx = t * 64 + lane;
        float4 m4 = Mr[idx];
        float4 v4 = ((const float4*)Vcur)[idx];
        s += m4.x * v4.x + m4.y * v4.y + m4.z * v4.z + m4.w * v4.w;
      }
#pragma unroll
      for (int off = 32; off; off >>= 1) s += __shfl_down(s, off);
      if (lane == 0) {
        float zv = s - beta_prev * Vprev[r];
        unsigned long long pk = ((unsigned long long)(unsigned)j << 32) |
                                (unsigned long long)(unsigned)__float_as_uint(zv);
        __hip_atomic_store(&Z[r], pk, __ATOMIC_RELAXED, AGENT);
      }
    }

    // hoist own v-slice reads (LDS) ahead of the poll — free overlap
    float va[4];
#pragma unroll
    for (int t = 0; t < 4; ++t) va[t] = Vcur[t * 512 + tid];

    unsigned long long w4[4];
    int rounds = 0;
    for (;;) {
      bool ok = true;
#pragma unroll
      for (int t = 0; t < 4; ++t) {
        w4[t] = __hip_atomic_load(&Z[t * 512 + tid], __ATOMIC_RELAXED, AGENT);
        ok &= ((unsigned)(w4[t] >> 32) == (unsigned)j);
      }
      if (ok) break;
      if (rounds == 1)      __builtin_amdgcn_s_sleep(1);   //  64 clk
      else if (rounds == 2) __builtin_amdgcn_s_sleep(2);   // 128 clk
      else if (rounds >= 3) __builtin_amdgcn_s_sleep(8);   // 512 clk
      ++rounds;
    }
    float za[4];
    float pa = 0.f;
#pragma unroll
    for (int t = 0; t < 4; ++t) {
      za[t] = __uint_as_float((unsigned)w4[t]);
      pa += za[t] * va[t];
    }
    float alpha = block_sum8(pa, red);
    float pb = 0.f;
#pragma unroll
    for (int t = 0; t < 4; ++t) {
      float rsd = za[t] - alpha * va[t];
      pb += rsd * rsd;
    }
    float beta2 = block_sum8(pb, red);
    float beta = sqrtf(fmaxf(beta2, 1e-30f));
    float invb = 1.f / beta;
    if (tid == 0) { al[j] = alpha; b2[j] = beta2; }
#pragma unroll
    for (int t = 0; t < 4; ++t) {
      int i = t * 512 + tid;
      Vprev[i] = (za[t] - alpha * va[t]) * invb;
    }
    float* tmp = Vprev; Vprev = Vcur; Vcur = tmp;
    beta_prev = beta;
    __syncthreads();
  }

  // ---- extreme eigenvalues of T via Sturm bisection (block 0) ----
  if (b == 0) {
    if (tid == 0) {                                  // Gershgorin bounds on T
      float lo = 1e30f, hi = -1e30f;
      for (int i = 1; i <= LK; ++i) {
        float bl = (i > 1) ? sqrtf(b2[i - 1]) : 0.f;
        float br = (i < LK) ? sqrtf(b2[i]) : 0.f;
        lo = fminf(lo, al[i] - bl - br);
        hi = fmaxf(hi, al[i] + bl + br);
      }
      bnds[0] = lo; bnds[1] = hi;
    }
    __syncthreads();
    if (wave < 2) {                 // wave 0 -> lambda_min, wave 1 -> lambda_max
      const int tcount = (wave == 0) ? 1 : LK;
      float lo = bnds[0], hi = bnds[1];
      for (int round = 0; round < 4; ++round) {
        float x = lo + (hi - lo) * (float)(lane + 1) * (1.f / 65.f);
        int cnt = 0;                                 // #eigs of T below x
        float d = al[1] - x;
        if (fabsf(d) < 1e-25f) d = -1e-25f;
        if (d < 0.f) cnt++;
        for (int i = 2; i <= LK; ++i) {
          d = (al[i] - x) - b2[i - 1] / d;
          if (fabsf(d) < 1e-25f) d = -1e-25f;
          if (d < 0.f) cnt++;
        }
        bool ab = (cnt >= tcount);                   // x is above the target eig
        float cand_hi = ab ? x : hi;
        float cand_lo = ab ? lo : x;
#pragma unroll
        for (int off = 32; off; off >>= 1) {
          cand_hi = fminf(cand_hi, __shfl_down(cand_hi, off));
          cand_lo = fmaxf(cand_lo, __shfl_down(cand_lo, off));
        }
        cand_hi = __shfl(cand_hi, 0);
        cand_lo = __shfl(cand_lo, 0);
        hi = cand_hi;
        lo = fminf(cand_lo, hi);
      }
      if (lane == 0) res[wave] = 0.5f * (lo + hi);
    }
    __syncthreads();
    if (tid == 0) {
      float lmin = fmaxf(res[0], 1e-12f);
      float lmax = fmaxf(res[1], 1e-12f);
      out[0] = logf(lmax) - logf(lmin);
    }
  }
}

extern "C" void kernel_launch(void* const* d_in, const int* in_sizes, int n_in,
                              void* d_out, int out_size, void* d_ws, size_t ws_size,
                              hipStream_t stream) {
  const float* pred = (const float*)d_in[0];
  const float* scal = (const float*)d_in[1];
  const float* W    = (const float*)d_in[2];
  const int*   rows = (const int*)d_in[3];
  const int*   cols = (const int*)d_in[4];
  float* out = (float*)d_out;

  // workspace layout (peak ~34.2 MB):
  //  [0,8MB)   : Hf fp16
  //  [8,16MB)  : Gh fp16 (G = L*Wh)
  //  [16,32MB) : M fp32
  //  [32MB,..) : cntR 8KB | cntC 8KB | binRc 512KB | binRv 512KB |
  //              binCr 512KB | binCv 512KB | Z0 16KB | Z1 16KB
  char* ws = (char*)d_ws;
  const size_t MB = 1024 * 1024;
  unsigned short* Hf = (unsigned short*)(ws);
  unsigned short* Gh = (unsigned short*)(ws + 8 * MB);
  float* M = (float*)(ws + 16 * MB);
  char* ctrl = ws + 32 * MB;
  unsigned* cntR = (unsigned*)(ctrl);
  unsigned* cntC = (unsigned*)(ctrl + 8192);
  int*      binRc = (int*)(ctrl + 16384);
  float*    binRv = (float*)(ctrl + 16384 + 524288);
  int*      binCr = (int*)(ctrl + 16384 + 2 * 524288);
  float*    binCv = (float*)(ctrl + 16384 + 3 * 524288);
  unsigned long long* Z0 = (unsigned long long*)(ctrl + 16384 + 4 * 524288);
  unsigned long long* Z1 = (unsigned long long*)(ctrl + 16384 + 4 * 524288 + 16384);

  convert_kernel<<<4096, 256, 0, stream>>>(W, Hf, cntR, cntC);
  fill_kernel<<<NNZ / 256, 256, 0, stream>>>(pred, scal, rows, cols,
                                             cntR, binRc, binRv, cntC, binCr, binCv);
  gatherG_kernel<<<2048, 256, 0, stream>>>(cntR, binRc, binRv, Hf, Gh);  // G = L*Wh
  gemmM_kernel<<<136, 512, 0, stream>>>(Gh, M);    // M = GG^T/N + I (128x128 tiles)
  lanczos_kernel<<<NBL, 512, 0, stream>>>(M, cntR, binRc, binRv,
                                          cntC, binCr, binCv, Z0, Z1, out);
}